// Round 11
// baseline (93.814 us; speedup 1.0000x reference)
//
#include <hip/hip_runtime.h>
#include <hip/hip_bf16.h>
#include <stdint.h>

#define NN 50000
#define NE 1600000
#define BSH 7            // bucket = 128 dst nodes
#define NBK 391          // ceil(NN/128)
#define CAP 4608         // slots per bucket (mean 4092, sigma~64, +8 sigma)
#define NSB 256          // edge-pass blocks
#define ECH 6250         // edges per block (NSB*ECH == NE exactly)
#define EPAIR 3125       // int2 pairs per block

// ---------------- launch 1: [wcombo: block 0 | hist: blocks 1..256] ----------------
__global__ __launch_bounds__(1024) void k_iw(const float* __restrict__ W1, const float* __restrict__ b1,
                                             const float* __restrict__ W2, const float* __restrict__ b2,
                                             const float* __restrict__ Wc, const float* __restrict__ bc,
                                             float* __restrict__ Wcombo, float* __restrict__ c12,
                                             const int* __restrict__ dst, int* __restrict__ bh){
  const int t = threadIdx.x;
  if (blockIdx.x == 0){
    __shared__ float M1[1024];
    { // M1 = W2@Wc [128,8], one element per thread
      int k = t >> 3, c = t & 7;
      float s = 0.f;
      for (int j = 0; j < 64; ++j) s += W2[k * 64 + j] * Wc[j * 8 + c];
      M1[t] = s;
    }
    __syncthreads();
    for (int idx = t; idx < 2048; idx += 1024){
      int i = idx >> 3, c = idx & 7;
      float s = 0.f;
      for (int k = 0; k < 128; ++k) s += W1[i * 128 + k] * M1[k * 8 + c];
      Wcombo[idx] = s;
    }
    if (t < 8){
      float s = 0.f;
      for (int k = 0; k < 128; ++k) s += b1[k] * M1[k * 8 + t];
      c12[t] = s;
    } else if (t < 16){
      int c = t - 8;
      float s = bc[c];
      for (int k = 0; k < 64; ++k) s += b2[k] * Wc[k * 8 + c];
      c12[t] = s;
    }
  } else {
    __shared__ int h[4 * NBK];
    const int hb = blockIdx.x - 1;
    for (int i = t; i < 4 * NBK; i += 1024) h[i] = 0;
    __syncthreads();
    const int g = (t >> 8) * NBK;      // 4-way split histogram
    const int2* dp = (const int2*)(dst + hb * ECH);
    for (int i = t; i < EPAIR; i += 1024){
      int2 d = dp[i];
      atomicAdd(&h[g + (d.x >> BSH)], 1);
      atomicAdd(&h[g + (d.y >> BSH)], 1);
    }
    __syncthreads();
    for (int i = t; i < NBK; i += 1024)
      bh[(size_t)hb * NBK + i] = h[i] + h[NBK + i] + h[2 * NBK + i] + h[3 * NBK + i];
  }
}

// ---------------- launch 2: [bscan: blocks 0..97 (4 buckets each) | Yraw: blocks 98+] ----------------
__global__ __launch_bounds__(1024) void k_by(const int* __restrict__ bh, int* __restrict__ boff,
                                             int* __restrict__ btot,
                                             const float* __restrict__ X, const float* __restrict__ Wcombo,
                                             float* __restrict__ Yraw){
  const int t = threadIdx.x;
  if (blockIdx.x < 98){
    __shared__ int lds[1024];
    const int tt = t & 255;
    const int b = blockIdx.x * 4 + (t >> 8);
    const bool ok = b < NBK;
    int v = ok ? bh[(size_t)tt * NBK + b] : 0;
    lds[t] = v;
    __syncthreads();
    for (int ofs = 1; ofs < 256; ofs <<= 1){
      int tmp = (tt >= ofs) ? lds[t - ofs] : 0;
      __syncthreads();
      lds[t] += tmp;
      __syncthreads();
    }
    if (ok) boff[(size_t)tt * NBK + b] = lds[t] - v;
    if (ok && tt == 255) btot[b] = lds[t];
  } else {
    __shared__ float Wl[2048];
    for (int i = t; i < 2048; i += 1024) Wl[i] = Wcombo[i];
    __syncthreads();
    int gid = (blockIdx.x - 98) * 1024 + t;
    int row = gid >> 3, c = gid & 7;
    if (row >= NN) return;
    const float* Xr = X + (size_t)row * 256;
    float acc = 0.f;
    #pragma unroll 8
    for (int k = 0; k < 256; k += 4){
      float4 x = *(const float4*)(Xr + k);
      acc += x.x * Wl[k * 8 + c] + x.y * Wl[(k + 1) * 8 + c]
           + x.z * Wl[(k + 2) * 8 + c] + x.w * Wl[(k + 3) * 8 + c];
    }
    Yraw[(size_t)row * 8 + c] = acc;
  }
}

// ---------------- launch 3: scatter packed (src<<16 | dst), 16 waves/block ----------------
__global__ __launch_bounds__(1024) void k_scat(const int* __restrict__ src, const int* __restrict__ dst,
                                               const int* __restrict__ boff, uint32_t* __restrict__ ebuf){
  __shared__ int ctr[NBK];
  const int t = threadIdx.x;
  for (int i = t; i < NBK; i += 1024)
    ctr[i] = i * CAP + boff[(size_t)blockIdx.x * NBK + i];
  __syncthreads();
  const int2* dp = (const int2*)(dst + blockIdx.x * ECH);
  const int2* sp = (const int2*)(src + blockIdx.x * ECH);
  for (int i = t; i < EPAIR; i += 1024){
    int2 d = dp[i];
    int2 s = sp[i];
    int p0 = atomicAdd(&ctr[d.x >> BSH], 1);
    ebuf[p0] = ((uint32_t)s.x << 16) | (uint32_t)d.x;
    int p1 = atomicAdd(&ctr[d.y >> BSH], 1);
    ebuf[p1] = ((uint32_t)s.y << 16) | (uint32_t)d.y;
  }
}

// ---------------- launch 4: per-bucket LDS-staged degree + scan + dinv + offs2 + csr ----------------
__global__ __launch_bounds__(512) void k_csr(const uint32_t* __restrict__ ebuf, const int* __restrict__ btot,
                                             float* __restrict__ dinv, int2* __restrict__ offs2,
                                             unsigned short* __restrict__ csr){
  __shared__ uint32_t lede[CAP];
  __shared__ unsigned short lcsr[CAP];
  __shared__ int h[128];
  __shared__ int sb[128];
  const int t = threadIdx.x;
  const int b = blockIdx.x;
  const int base = b * CAP;
  const int cnt = btot[b];
  for (int i = t; i < cnt; i += 512) lede[i] = ebuf[base + i];
  if (t < 128) h[t] = 0;
  __syncthreads();
  for (int i = t; i < cnt; i += 512)
    atomicAdd(&h[lede[i] & 127], 1);
  __syncthreads();
  int deg = (t < 128) ? h[t] : 0;
  for (int ofs = 1; ofs < 128; ofs <<= 1){
    int tv = (t >= ofs && t < 128) ? h[t - ofs] : 0;
    __syncthreads();
    if (t < 128) h[t] += tv;
    __syncthreads();
  }
  int excl = (t < 128) ? (h[t] - deg) : 0;
  int node = (b << BSH) + t;
  if (t < 128 && node < NN){
    dinv[node] = rsqrtf((float)(deg + 1));
    offs2[node] = make_int2(base + excl, base + excl + deg);
  }
  __syncthreads();
  if (t < 128) sb[t] = excl;
  __syncthreads();
  for (int i = t; i < cnt; i += 512){
    uint32_t v = lede[i];
    int p = atomicAdd(&sb[v & 127], 1);
    lcsr[p] = (unsigned short)(v >> 16);
  }
  __syncthreads();
  uint32_t* dstw = (uint32_t*)(csr + base);
  const uint32_t* srcw = (const uint32_t*)lcsr;
  int nw = (cnt + 1) >> 1;
  for (int i = t; i < nw; i += 512) dstw[i] = srcw[i];
}

// ---------------- launch 5: agg pass 1, 8 lanes/node ----------------
// U = di^2*(sum_s dinv_s*Yraw_s + di*Yraw_d);  V = di*(sum_s dinv_s + di)
__global__ __launch_bounds__(256) void k_agg1(const unsigned short* __restrict__ csr, const int2* __restrict__ offs2,
                                              const float* __restrict__ dinv, const float* __restrict__ Y,
                                              float* __restrict__ U, float* __restrict__ V){
  int gid = blockIdx.x * 256 + threadIdx.x;
  int node = gid >> 3, c = gid & 7;
  if (node >= NN) return;
  int2 oe = offs2[node];
  int e = oe.x;
  const int e1 = oe.y;
  float a = 0.f, vd = 0.f;
  for (; e + 4 <= e1; e += 4){
    int s0 = csr[e], s1 = csr[e + 1], s2 = csr[e + 2], s3 = csr[e + 3];
    float d0 = dinv[s0], d1 = dinv[s1], d2 = dinv[s2], d3 = dinv[s3];
    float y0 = Y[(size_t)s0 * 8 + c], y1 = Y[(size_t)s1 * 8 + c];
    float y2 = Y[(size_t)s2 * 8 + c], y3 = Y[(size_t)s3 * 8 + c];
    a += (d0 * y0 + d1 * y1) + (d2 * y2 + d3 * y3);
    vd += (d0 + d1) + (d2 + d3);
  }
  for (; e < e1; ++e){
    int s0 = csr[e];
    float d0 = dinv[s0];
    a += d0 * Y[(size_t)s0 * 8 + c];
    vd += d0;
  }
  float di = dinv[node];
  U[(size_t)node * 8 + c] = di * di * (a + di * Y[(size_t)node * 8 + c]);
  if (c == 0) V[node] = di * (vd + di);
}

// ---------------- launch 6: agg pass 2: out = di*(sum_s U_s + U_d) + V*c1 + c2 ----------------
__global__ __launch_bounds__(256) void k_agg2(const unsigned short* __restrict__ csr, const int2* __restrict__ offs2,
                                              const float* __restrict__ dinv, const float* __restrict__ U,
                                              const float* __restrict__ V, const float* __restrict__ c12,
                                              float* __restrict__ O){
  int gid = blockIdx.x * 256 + threadIdx.x;
  int node = gid >> 3, c = gid & 7;
  if (node >= NN) return;
  int2 oe = offs2[node];
  int e = oe.x;
  const int e1 = oe.y;
  float a = 0.f;
  for (; e + 4 <= e1; e += 4){
    int s0 = csr[e], s1 = csr[e + 1], s2 = csr[e + 2], s3 = csr[e + 3];
    float y0 = U[(size_t)s0 * 8 + c], y1 = U[(size_t)s1 * 8 + c];
    float y2 = U[(size_t)s2 * 8 + c], y3 = U[(size_t)s3 * 8 + c];
    a += (y0 + y1) + (y2 + y3);
  }
  for (; e < e1; ++e){
    int s0 = csr[e];
    a += U[(size_t)s0 * 8 + c];
  }
  float di = dinv[node];
  O[(size_t)node * 8 + c] = di * (a + U[(size_t)node * 8 + c]) + V[node] * c12[c] + c12[8 + c];
}

extern "C" void kernel_launch(void* const* d_in, const int* in_sizes, int n_in,
                              void* d_out, int out_size, void* d_ws, size_t ws_size,
                              hipStream_t stream) {
  const float* seq = (const float*)d_in[0];
  const int*   ei  = (const int*)d_in[1];
  const int*   esrc = ei;
  const int*   edst = ei + NE;
  const float* W1 = (const float*)d_in[2];
  const float* b1 = (const float*)d_in[3];
  const float* W2 = (const float*)d_in[4];
  const float* b2 = (const float*)d_in[5];
  const float* Wc = (const float*)d_in[6];
  const float* bc = (const float*)d_in[7];
  float* out = (float*)d_out;

  char* ws = (char*)d_ws;
  size_t o = 0;
  auto alloc = [&](size_t bytes) -> void* {
    void* p = ws + o;
    o += (bytes + 255) & ~(size_t)255;
    return p;
  };
  int*      bh    = (int*)alloc((size_t)NSB * NBK * 4);
  int*      boff  = (int*)alloc((size_t)NSB * NBK * 4);
  int*      btot  = (int*)alloc((size_t)NBK * 4);
  uint32_t* ebuf  = (uint32_t*)alloc((size_t)NBK * CAP * 4);
  unsigned short* csr = (unsigned short*)alloc((size_t)NBK * CAP * 2);
  int2*     offs2 = (int2*)alloc((size_t)NN * 8);
  float*    dinv  = (float*)alloc((size_t)NN * 4);
  float*    Wcb   = (float*)alloc(2048 * 4);
  float*    c12   = (float*)alloc(16 * 4);
  float*    Yraw  = (float*)alloc((size_t)NN * 8 * 4);
  float*    U     = (float*)alloc((size_t)NN * 8 * 4);
  float*    V     = (float*)alloc((size_t)NN * 4);

  k_iw     <<<1 + NSB, 1024, 0, stream>>>(W1, b1, W2, b2, Wc, bc, Wcb, c12, edst, bh);
  k_by     <<<98 + 391, 1024, 0, stream>>>(bh, boff, btot, seq, Wcb, Yraw);
  k_scat   <<<NSB, 1024, 0, stream>>>(esrc, edst, boff, ebuf);
  k_csr    <<<NBK, 512, 0, stream>>>(ebuf, btot, dinv, offs2, csr);
  k_agg1   <<<1563, 256, 0, stream>>>(csr, offs2, dinv, Yraw, U, V);
  k_agg2   <<<1563, 256, 0, stream>>>(csr, offs2, dinv, U, V, c12, out);
}

// Round 13
// 91.435 us; speedup vs baseline: 1.0260x; 1.0260x over previous
//
#include <hip/hip_runtime.h>
#include <hip/hip_bf16.h>
#include <stdint.h>

#define NN 50000
#define NE 1600000
#define BSH 7            // bucket = 128 dst nodes
#define NBK 391          // ceil(NN/128)
#define CAP 4608         // slots per bucket (mean 4096, sigma~64, +8 sigma)
#define NSB 256          // edge-pass blocks
#define ECH 6250         // edges per block (NSB*ECH == NE exactly)
#define EPAIR 3125       // int2 pairs per block

// ---------------- launch 1: [wcombo: block 0 | hist: blocks 1..256] ----------------
__global__ __launch_bounds__(1024) void k_iw(const float* __restrict__ W1, const float* __restrict__ b1,
                                             const float* __restrict__ W2, const float* __restrict__ b2,
                                             const float* __restrict__ Wc, const float* __restrict__ bc,
                                             float* __restrict__ Wcombo, float* __restrict__ c12,
                                             const int* __restrict__ dst, int* __restrict__ bh){
  const int t = threadIdx.x;
  if (blockIdx.x == 0){
    __shared__ float M1[1024];
    { // M1 = W2@Wc [128,8], one element per thread
      int k = t >> 3, c = t & 7;
      float s = 0.f;
      for (int j = 0; j < 64; ++j) s += W2[k * 64 + j] * Wc[j * 8 + c];
      M1[t] = s;
    }
    __syncthreads();
    for (int idx = t; idx < 2048; idx += 1024){
      int i = idx >> 3, c = idx & 7;
      float s = 0.f;
      for (int k = 0; k < 128; ++k) s += W1[i * 128 + k] * M1[k * 8 + c];
      Wcombo[idx] = s;
    }
    if (t < 8){
      float s = 0.f;
      for (int k = 0; k < 128; ++k) s += b1[k] * M1[k * 8 + t];
      c12[t] = s;
    } else if (t < 16){
      int c = t - 8;
      float s = bc[c];
      for (int k = 0; k < 64; ++k) s += b2[k] * Wc[k * 8 + c];
      c12[t] = s;
    }
  } else {
    __shared__ int h[4 * NBK];
    const int hb = blockIdx.x - 1;
    for (int i = t; i < 4 * NBK; i += 1024) h[i] = 0;
    __syncthreads();
    const int g = (t >> 8) * NBK;      // 4-way split histogram
    const int2* dp = (const int2*)(dst + hb * ECH);
    for (int i = t; i < EPAIR; i += 1024){
      int2 d = dp[i];
      atomicAdd(&h[g + (d.x >> BSH)], 1);
      atomicAdd(&h[g + (d.y >> BSH)], 1);
    }
    __syncthreads();
    for (int i = t; i < NBK; i += 1024)
      bh[(size_t)hb * NBK + i] = h[i] + h[NBK + i] + h[2 * NBK + i] + h[3 * NBK + i];
  }
}

// ---------------- launch 2: per-bucket exclusive scan over the NSB blocks ----------------
__global__ __launch_bounds__(NSB) void k_bscan(const int* __restrict__ bh, int* __restrict__ boff,
                                               int* __restrict__ btot){
  __shared__ int lds[NSB];
  const int b = blockIdx.x;
  int v = bh[(size_t)threadIdx.x * NBK + b];
  lds[threadIdx.x] = v;
  __syncthreads();
  for (int ofs = 1; ofs < NSB; ofs <<= 1){
    int t = (threadIdx.x >= ofs) ? lds[threadIdx.x - ofs] : 0;
    __syncthreads();
    lds[threadIdx.x] += t;
    __syncthreads();
  }
  boff[(size_t)threadIdx.x * NBK + b] = lds[threadIdx.x] - v;
  if (threadIdx.x == NSB - 1) btot[b] = lds[NSB - 1];
}

// ---------------- launch 3: [scat: blocks 0..255 | Yraw: blocks 256..646] ----------------
__global__ __launch_bounds__(1024) void k_sy(const int* __restrict__ src, const int* __restrict__ dst,
                                             const int* __restrict__ boff, uint32_t* __restrict__ ebuf,
                                             const float* __restrict__ X, const float* __restrict__ Wcombo,
                                             float* __restrict__ Yraw){
  const int t = threadIdx.x;
  if (blockIdx.x < NSB){
    __shared__ int ctr[NBK];
    for (int i = t; i < NBK; i += 1024)
      ctr[i] = i * CAP + boff[(size_t)blockIdx.x * NBK + i];
    __syncthreads();
    const int2* dp = (const int2*)(dst + blockIdx.x * ECH);
    const int2* sp = (const int2*)(src + blockIdx.x * ECH);
    for (int i = t; i < EPAIR; i += 1024){
      int2 d = dp[i];
      int2 s = sp[i];
      int p0 = atomicAdd(&ctr[d.x >> BSH], 1);
      ebuf[p0] = ((uint32_t)s.x << 16) | (uint32_t)d.x;
      int p1 = atomicAdd(&ctr[d.y >> BSH], 1);
      ebuf[p1] = ((uint32_t)s.y << 16) | (uint32_t)d.y;
    }
  } else {
    __shared__ float Wl[2048];
    for (int i = t; i < 2048; i += 1024) Wl[i] = Wcombo[i];
    __syncthreads();
    int gid = (blockIdx.x - NSB) * 1024 + t;
    int row = gid >> 3, c = gid & 7;
    if (row >= NN) return;
    const float* Xr = X + (size_t)row * 256;
    float acc = 0.f;
    #pragma unroll 8
    for (int k = 0; k < 256; k += 4){
      float4 x = *(const float4*)(Xr + k);
      acc += x.x * Wl[k * 8 + c] + x.y * Wl[(k + 1) * 8 + c]
           + x.z * Wl[(k + 2) * 8 + c] + x.w * Wl[(k + 3) * 8 + c];
    }
    Yraw[(size_t)row * 8 + c] = acc;
  }
}

// ---------------- launch 4: per-bucket LDS-staged degree + scan + dinv + offs2 + csr ----------------
__global__ __launch_bounds__(512) void k_csr(const uint32_t* __restrict__ ebuf, const int* __restrict__ btot,
                                             float* __restrict__ dinv, int2* __restrict__ offs2,
                                             unsigned short* __restrict__ csr){
  __shared__ uint32_t lede[CAP];
  __shared__ unsigned short lcsr[CAP];
  __shared__ int h[128];
  __shared__ int sb[128];
  const int t = threadIdx.x;
  const int b = blockIdx.x;
  const int base = b * CAP;
  const int cnt = btot[b];
  for (int i = t; i < cnt; i += 512) lede[i] = ebuf[base + i];
  if (t < 128) h[t] = 0;
  __syncthreads();
  for (int i = t; i < cnt; i += 512)
    atomicAdd(&h[lede[i] & 127], 1);
  __syncthreads();
  int deg = (t < 128) ? h[t] : 0;
  for (int ofs = 1; ofs < 128; ofs <<= 1){
    int tv = (t >= ofs && t < 128) ? h[t - ofs] : 0;
    __syncthreads();
    if (t < 128) h[t] += tv;
    __syncthreads();
  }
  int excl = (t < 128) ? (h[t] - deg) : 0;
  int node = (b << BSH) + t;
  if (t < 128 && node < NN){
    dinv[node] = rsqrtf((float)(deg + 1));
    offs2[node] = make_int2(base + excl, base + excl + deg);
  }
  __syncthreads();
  if (t < 128) sb[t] = excl;
  __syncthreads();
  for (int i = t; i < cnt; i += 512){
    uint32_t v = lede[i];
    int p = atomicAdd(&sb[v & 127], 1);
    lcsr[p] = (unsigned short)(v >> 16);
  }
  __syncthreads();
  uint32_t* dstw = (uint32_t*)(csr + base);
  const uint32_t* srcw = (const uint32_t*)lcsr;
  int nw = (cnt + 1) >> 1;
  for (int i = t; i < nw; i += 512) dstw[i] = srcw[i];
}

// ---------------- launch 5: agg pass 1, 8 lanes/node ----------------
// U = di^2*(sum_s dinv_s*Yraw_s + di*Yraw_d);  V = di*(sum_s dinv_s + di)
__global__ __launch_bounds__(256) void k_agg1(const unsigned short* __restrict__ csr, const int2* __restrict__ offs2,
                                              const float* __restrict__ dinv, const float* __restrict__ Y,
                                              float* __restrict__ U, float* __restrict__ V){
  int gid = blockIdx.x * 256 + threadIdx.x;
  int node = gid >> 3, c = gid & 7;
  if (node >= NN) return;
  int2 oe = offs2[node];
  int e = oe.x;
  const int e1 = oe.y;
  float a = 0.f, vd = 0.f;
  for (; e + 4 <= e1; e += 4){
    int s0 = csr[e], s1 = csr[e + 1], s2 = csr[e + 2], s3 = csr[e + 3];
    float d0 = dinv[s0], d1 = dinv[s1], d2 = dinv[s2], d3 = dinv[s3];
    float y0 = Y[(size_t)s0 * 8 + c], y1 = Y[(size_t)s1 * 8 + c];
    float y2 = Y[(size_t)s2 * 8 + c], y3 = Y[(size_t)s3 * 8 + c];
    a += (d0 * y0 + d1 * y1) + (d2 * y2 + d3 * y3);
    vd += (d0 + d1) + (d2 + d3);
  }
  for (; e < e1; ++e){
    int s0 = csr[e];
    float d0 = dinv[s0];
    a += d0 * Y[(size_t)s0 * 8 + c];
    vd += d0;
  }
  float di = dinv[node];
  U[(size_t)node * 8 + c] = di * di * (a + di * Y[(size_t)node * 8 + c]);
  if (c == 0) V[node] = di * (vd + di);
}

// ---------------- launch 6: agg pass 2: out = di*(sum_s U_s + U_d) + V*c1 + c2 ----------------
__global__ __launch_bounds__(256) void k_agg2(const unsigned short* __restrict__ csr, const int2* __restrict__ offs2,
                                              const float* __restrict__ dinv, const float* __restrict__ U,
                                              const float* __restrict__ V, const float* __restrict__ c12,
                                              float* __restrict__ O){
  int gid = blockIdx.x * 256 + threadIdx.x;
  int node = gid >> 3, c = gid & 7;
  if (node >= NN) return;
  int2 oe = offs2[node];
  int e = oe.x;
  const int e1 = oe.y;
  float a = 0.f;
  for (; e + 4 <= e1; e += 4){
    int s0 = csr[e], s1 = csr[e + 1], s2 = csr[e + 2], s3 = csr[e + 3];
    float y0 = U[(size_t)s0 * 8 + c], y1 = U[(size_t)s1 * 8 + c];
    float y2 = U[(size_t)s2 * 8 + c], y3 = U[(size_t)s3 * 8 + c];
    a += (y0 + y1) + (y2 + y3);
  }
  for (; e < e1; ++e){
    int s0 = csr[e];
    a += U[(size_t)s0 * 8 + c];
  }
  float di = dinv[node];
  O[(size_t)node * 8 + c] = di * (a + U[(size_t)node * 8 + c]) + V[node] * c12[c] + c12[8 + c];
}

extern "C" void kernel_launch(void* const* d_in, const int* in_sizes, int n_in,
                              void* d_out, int out_size, void* d_ws, size_t ws_size,
                              hipStream_t stream) {
  const float* seq = (const float*)d_in[0];
  const int*   ei  = (const int*)d_in[1];
  const int*   esrc = ei;
  const int*   edst = ei + NE;
  const float* W1 = (const float*)d_in[2];
  const float* b1 = (const float*)d_in[3];
  const float* W2 = (const float*)d_in[4];
  const float* b2 = (const float*)d_in[5];
  const float* Wc = (const float*)d_in[6];
  const float* bc = (const float*)d_in[7];
  float* out = (float*)d_out;

  char* ws = (char*)d_ws;
  size_t o = 0;
  auto alloc = [&](size_t bytes) -> void* {
    void* p = ws + o;
    o += (bytes + 255) & ~(size_t)255;
    return p;
  };
  int*      bh    = (int*)alloc((size_t)NSB * NBK * 4);
  int*      boff  = (int*)alloc((size_t)NSB * NBK * 4);
  int*      btot  = (int*)alloc((size_t)NBK * 4);
  uint32_t* ebuf  = (uint32_t*)alloc((size_t)NBK * CAP * 4);
  unsigned short* csr = (unsigned short*)alloc((size_t)NBK * CAP * 2);
  int2*     offs2 = (int2*)alloc((size_t)NN * 8);
  float*    dinv  = (float*)alloc((size_t)NN * 4);
  float*    Wcb   = (float*)alloc(2048 * 4);
  float*    c12   = (float*)alloc(16 * 4);
  float*    Yraw  = (float*)alloc((size_t)NN * 8 * 4);
  float*    U     = (float*)alloc((size_t)NN * 8 * 4);
  float*    V     = (float*)alloc((size_t)NN * 4);

  k_iw    <<<1 + NSB, 1024, 0, stream>>>(W1, b1, W2, b2, Wc, bc, Wcb, c12, edst, bh);
  k_bscan <<<NBK, NSB, 0, stream>>>(bh, boff, btot);
  k_sy    <<<NSB + 391, 1024, 0, stream>>>(esrc, edst, boff, ebuf, seq, Wcb, Yraw);
  k_csr   <<<NBK, 512, 0, stream>>>(ebuf, btot, dinv, offs2, csr);
  k_agg1  <<<1563, 256, 0, stream>>>(csr, offs2, dinv, Yraw, U, V);
  k_agg2  <<<1563, 256, 0, stream>>>(csr, offs2, dinv, U, V, c12, out);
}

// Round 14
// 86.656 us; speedup vs baseline: 1.0826x; 1.0552x over previous
//
#include <hip/hip_runtime.h>
#include <hip/hip_bf16.h>
#include <stdint.h>

#define NN 50000
#define NE 1600000
#define BSH 7            // bucket = 128 dst nodes
#define NBK 391          // ceil(NN/128)
#define CAP 4608         // slots per bucket (mean 4096, sigma~64, +8 sigma)
#define NSB 256          // edge-pass blocks
#define ECH 6250         // edges per block (NSB*ECH == NE exactly)
#define EPAIR 3125       // int2 pairs per block

// ---------------- launch 1: [wcombo: block 0 | hist: blocks 1..256] ----------------
__global__ __launch_bounds__(1024) void k_iw(const float* __restrict__ W1, const float* __restrict__ b1,
                                             const float* __restrict__ W2, const float* __restrict__ b2,
                                             const float* __restrict__ Wc, const float* __restrict__ bc,
                                             float* __restrict__ Wcombo, float* __restrict__ c12,
                                             const int* __restrict__ dst, int* __restrict__ bh){
  const int t = threadIdx.x;
  if (blockIdx.x == 0){
    __shared__ float M1[1024];
    { // M1 = W2@Wc [128,8], one element per thread
      int k = t >> 3, c = t & 7;
      float s = 0.f;
      for (int j = 0; j < 64; ++j) s += W2[k * 64 + j] * Wc[j * 8 + c];
      M1[t] = s;
    }
    __syncthreads();
    for (int idx = t; idx < 2048; idx += 1024){
      int i = idx >> 3, c = idx & 7;
      float s = 0.f;
      for (int k = 0; k < 128; ++k) s += W1[i * 128 + k] * M1[k * 8 + c];
      Wcombo[idx] = s;
    }
    if (t < 8){
      float s = 0.f;
      for (int k = 0; k < 128; ++k) s += b1[k] * M1[k * 8 + t];
      c12[t] = s;
    } else if (t < 16){
      int c = t - 8;
      float s = bc[c];
      for (int k = 0; k < 64; ++k) s += b2[k] * Wc[k * 8 + c];
      c12[t] = s;
    }
  } else {
    __shared__ int h[4 * NBK];
    const int hb = blockIdx.x - 1;
    for (int i = t; i < 4 * NBK; i += 1024) h[i] = 0;
    __syncthreads();
    const int g = (t >> 8) * NBK;      // 4-way split histogram
    const int2* dp = (const int2*)(dst + hb * ECH);
    for (int i = t; i < EPAIR; i += 1024){
      int2 d = dp[i];
      atomicAdd(&h[g + (d.x >> BSH)], 1);
      atomicAdd(&h[g + (d.y >> BSH)], 1);
    }
    __syncthreads();
    for (int i = t; i < NBK; i += 1024)
      bh[(size_t)hb * NBK + i] = h[i] + h[NBK + i] + h[2 * NBK + i] + h[3 * NBK + i];
  }
}

// ---------------- launch 2: per-bucket exclusive scan over the NSB blocks ----------------
__global__ __launch_bounds__(NSB) void k_bscan(const int* __restrict__ bh, int* __restrict__ boff,
                                               int* __restrict__ btot){
  __shared__ int lds[NSB];
  const int b = blockIdx.x;
  int v = bh[(size_t)threadIdx.x * NBK + b];
  lds[threadIdx.x] = v;
  __syncthreads();
  for (int ofs = 1; ofs < NSB; ofs <<= 1){
    int t = (threadIdx.x >= ofs) ? lds[threadIdx.x - ofs] : 0;
    __syncthreads();
    lds[threadIdx.x] += t;
    __syncthreads();
  }
  boff[(size_t)threadIdx.x * NBK + b] = lds[threadIdx.x] - v;
  if (threadIdx.x == NSB - 1) btot[b] = lds[NSB - 1];
}

// ---------------- launch 3: [scat (LDS-staged): blocks 0..255 | Yraw: blocks 256..646] ----------------
__global__ __launch_bounds__(1024) void k_sy(const int* __restrict__ src, const int* __restrict__ dst,
                                             const int* __restrict__ bh, const int* __restrict__ boff,
                                             uint32_t* __restrict__ ebuf,
                                             const float* __restrict__ X, const float* __restrict__ Wcombo,
                                             float* __restrict__ Yraw){
  const int t = threadIdx.x;
  if (blockIdx.x < NSB){
    __shared__ uint32_t lbuf[ECH];     // 25 KB: block's edges grouped by bucket
    __shared__ int lcnt[NBK];
    __shared__ int lst[NBK];           // exclusive local segment start per bucket
    __shared__ int dbase[NBK];         // global dest base per bucket
    const int blk = blockIdx.x;
    int myc = 0;
    if (t < NBK){
      myc = bh[(size_t)blk * NBK + t];
      lst[t] = myc;
      lcnt[t] = 0;
      dbase[t] = t * CAP + boff[(size_t)blk * NBK + t];
    }
    __syncthreads();
    // exclusive scan of lst over NBK entries (Hillis-Steele, threads t<NBK)
    for (int ofs = 1; ofs < NBK; ofs <<= 1){
      int v = (t < NBK && t >= ofs) ? lst[t - ofs] : 0;
      __syncthreads();
      if (t < NBK) lst[t] += v;
      __syncthreads();
    }
    if (t < NBK) lst[t] -= myc;        // inclusive -> exclusive
    __syncthreads();
    // phase 1: scatter edges into LDS, grouped by bucket
    const int2* dp = (const int2*)(dst + blk * ECH);
    const int2* sp = (const int2*)(src + blk * ECH);
    for (int i = t; i < EPAIR; i += 1024){
      int2 d = dp[i];
      int2 s = sp[i];
      int b0 = d.x >> BSH;
      int p0 = atomicAdd(&lcnt[b0], 1);
      lbuf[lst[b0] + p0] = ((uint32_t)s.x << 16) | (uint32_t)d.x;
      int b1i = d.y >> BSH;
      int p1 = atomicAdd(&lcnt[b1i], 1);
      lbuf[lst[b1i] + p1] = ((uint32_t)s.y << 16) | (uint32_t)d.y;
    }
    __syncthreads();
    // phase 2: segment-local coalesced copy-out (runs of ~16 consecutive dest addresses)
    for (int k = t; k < ECH; k += 1024){
      uint32_t v = lbuf[k];
      int b = (int)(v & 0xFFFFu) >> BSH;
      ebuf[dbase[b] + (k - lst[b])] = v;
    }
  } else {
    __shared__ float Wl[2048];
    for (int i = t; i < 2048; i += 1024) Wl[i] = Wcombo[i];
    __syncthreads();
    int gid = (blockIdx.x - NSB) * 1024 + t;
    int row = gid >> 3, c = gid & 7;
    if (row >= NN) return;
    const float* Xr = X + (size_t)row * 256;
    float acc = 0.f;
    #pragma unroll 8
    for (int k = 0; k < 256; k += 4){
      float4 x = *(const float4*)(Xr + k);
      acc += x.x * Wl[k * 8 + c] + x.y * Wl[(k + 1) * 8 + c]
           + x.z * Wl[(k + 2) * 8 + c] + x.w * Wl[(k + 3) * 8 + c];
    }
    Yraw[(size_t)row * 8 + c] = acc;
  }
}

// ---------------- launch 4: per-bucket LDS-staged degree + scan + dinv + offs2 + csr ----------------
__global__ __launch_bounds__(512) void k_csr(const uint32_t* __restrict__ ebuf, const int* __restrict__ btot,
                                             float* __restrict__ dinv, int2* __restrict__ offs2,
                                             unsigned short* __restrict__ csr){
  __shared__ uint32_t lede[CAP];
  __shared__ unsigned short lcsr[CAP];
  __shared__ int h[128];
  __shared__ int sb[128];
  const int t = threadIdx.x;
  const int b = blockIdx.x;
  const int base = b * CAP;
  const int cnt = btot[b];
  for (int i = t; i < cnt; i += 512) lede[i] = ebuf[base + i];
  if (t < 128) h[t] = 0;
  __syncthreads();
  for (int i = t; i < cnt; i += 512)
    atomicAdd(&h[lede[i] & 127], 1);
  __syncthreads();
  int deg = (t < 128) ? h[t] : 0;
  for (int ofs = 1; ofs < 128; ofs <<= 1){
    int tv = (t >= ofs && t < 128) ? h[t - ofs] : 0;
    __syncthreads();
    if (t < 128) h[t] += tv;
    __syncthreads();
  }
  int excl = (t < 128) ? (h[t] - deg) : 0;
  int node = (b << BSH) + t;
  if (t < 128 && node < NN){
    dinv[node] = rsqrtf((float)(deg + 1));
    offs2[node] = make_int2(base + excl, base + excl + deg);
  }
  __syncthreads();
  if (t < 128) sb[t] = excl;
  __syncthreads();
  for (int i = t; i < cnt; i += 512){
    uint32_t v = lede[i];
    int p = atomicAdd(&sb[v & 127], 1);
    lcsr[p] = (unsigned short)(v >> 16);
  }
  __syncthreads();
  uint32_t* dstw = (uint32_t*)(csr + base);
  const uint32_t* srcw = (const uint32_t*)lcsr;
  int nw = (cnt + 1) >> 1;
  for (int i = t; i < nw; i += 512) dstw[i] = srcw[i];
}

// ---------------- launch 5: agg pass 1, 8 lanes/node ----------------
// U = di^2*(sum_s dinv_s*Yraw_s + di*Yraw_d);  V = di*(sum_s dinv_s + di)
__global__ __launch_bounds__(256) void k_agg1(const unsigned short* __restrict__ csr, const int2* __restrict__ offs2,
                                              const float* __restrict__ dinv, const float* __restrict__ Y,
                                              float* __restrict__ U, float* __restrict__ V){
  int gid = blockIdx.x * 256 + threadIdx.x;
  int node = gid >> 3, c = gid & 7;
  if (node >= NN) return;
  int2 oe = offs2[node];
  int e = oe.x;
  const int e1 = oe.y;
  float a = 0.f, vd = 0.f;
  for (; e + 4 <= e1; e += 4){
    int s0 = csr[e], s1 = csr[e + 1], s2 = csr[e + 2], s3 = csr[e + 3];
    float d0 = dinv[s0], d1 = dinv[s1], d2 = dinv[s2], d3 = dinv[s3];
    float y0 = Y[(size_t)s0 * 8 + c], y1 = Y[(size_t)s1 * 8 + c];
    float y2 = Y[(size_t)s2 * 8 + c], y3 = Y[(size_t)s3 * 8 + c];
    a += (d0 * y0 + d1 * y1) + (d2 * y2 + d3 * y3);
    vd += (d0 + d1) + (d2 + d3);
  }
  for (; e < e1; ++e){
    int s0 = csr[e];
    float d0 = dinv[s0];
    a += d0 * Y[(size_t)s0 * 8 + c];
    vd += d0;
  }
  float di = dinv[node];
  U[(size_t)node * 8 + c] = di * di * (a + di * Y[(size_t)node * 8 + c]);
  if (c == 0) V[node] = di * (vd + di);
}

// ---------------- launch 6: agg pass 2: out = di*(sum_s U_s + U_d) + V*c1 + c2 ----------------
__global__ __launch_bounds__(256) void k_agg2(const unsigned short* __restrict__ csr, const int2* __restrict__ offs2,
                                              const float* __restrict__ dinv, const float* __restrict__ U,
                                              const float* __restrict__ V, const float* __restrict__ c12,
                                              float* __restrict__ O){
  int gid = blockIdx.x * 256 + threadIdx.x;
  int node = gid >> 3, c = gid & 7;
  if (node >= NN) return;
  int2 oe = offs2[node];
  int e = oe.x;
  const int e1 = oe.y;
  float a = 0.f;
  for (; e + 4 <= e1; e += 4){
    int s0 = csr[e], s1 = csr[e + 1], s2 = csr[e + 2], s3 = csr[e + 3];
    float y0 = U[(size_t)s0 * 8 + c], y1 = U[(size_t)s1 * 8 + c];
    float y2 = U[(size_t)s2 * 8 + c], y3 = U[(size_t)s3 * 8 + c];
    a += (y0 + y1) + (y2 + y3);
  }
  for (; e < e1; ++e){
    int s0 = csr[e];
    a += U[(size_t)s0 * 8 + c];
  }
  float di = dinv[node];
  O[(size_t)node * 8 + c] = di * (a + U[(size_t)node * 8 + c]) + V[node] * c12[c] + c12[8 + c];
}

extern "C" void kernel_launch(void* const* d_in, const int* in_sizes, int n_in,
                              void* d_out, int out_size, void* d_ws, size_t ws_size,
                              hipStream_t stream) {
  const float* seq = (const float*)d_in[0];
  const int*   ei  = (const int*)d_in[1];
  const int*   esrc = ei;
  const int*   edst = ei + NE;
  const float* W1 = (const float*)d_in[2];
  const float* b1 = (const float*)d_in[3];
  const float* W2 = (const float*)d_in[4];
  const float* b2 = (const float*)d_in[5];
  const float* Wc = (const float*)d_in[6];
  const float* bc = (const float*)d_in[7];
  float* out = (float*)d_out;

  char* ws = (char*)d_ws;
  size_t o = 0;
  auto alloc = [&](size_t bytes) -> void* {
    void* p = ws + o;
    o += (bytes + 255) & ~(size_t)255;
    return p;
  };
  int*      bh    = (int*)alloc((size_t)NSB * NBK * 4);
  int*      boff  = (int*)alloc((size_t)NSB * NBK * 4);
  int*      btot  = (int*)alloc((size_t)NBK * 4);
  uint32_t* ebuf  = (uint32_t*)alloc((size_t)NBK * CAP * 4);
  unsigned short* csr = (unsigned short*)alloc((size_t)NBK * CAP * 2);
  int2*     offs2 = (int2*)alloc((size_t)NN * 8);
  float*    dinv  = (float*)alloc((size_t)NN * 4);
  float*    Wcb   = (float*)alloc(2048 * 4);
  float*    c12   = (float*)alloc(16 * 4);
  float*    Yraw  = (float*)alloc((size_t)NN * 8 * 4);
  float*    U     = (float*)alloc((size_t)NN * 8 * 4);
  float*    V     = (float*)alloc((size_t)NN * 4);

  k_iw    <<<1 + NSB, 1024, 0, stream>>>(W1, b1, W2, b2, Wc, bc, Wcb, c12, edst, bh);
  k_bscan <<<NBK, NSB, 0, stream>>>(bh, boff, btot);
  k_sy    <<<NSB + 391, 1024, 0, stream>>>(esrc, edst, bh, boff, ebuf, seq, Wcb, Yraw);
  k_csr   <<<NBK, 512, 0, stream>>>(ebuf, btot, dinv, offs2, csr);
  k_agg1  <<<1563, 256, 0, stream>>>(csr, offs2, dinv, Yraw, U, V);
  k_agg2  <<<1563, 256, 0, stream>>>(csr, offs2, dinv, U, V, c12, out);
}